// Round 8
// baseline (7880.785 us; speedup 1.0000x reference)
//
#include <hip/hip_runtime.h>
#include <hip/hip_bf16.h>

#define N_CHAR 128
#define EMBED  256
#define HIDDEN 1024
#define BATCH  64
#define SEQ    512
#define GB     8   // batch rows per group

typedef __attribute__((ext_vector_type(4))) float f32x4;

__device__ __forceinline__ float dot4(const f32x4 a, const f32x4 b) {
  return a.x * b.x + a.y * b.y + a.z * b.z + a.w * b.w;
}

// ---------------------------------------------------------------------------
// P[c][j] = sum_k embeddings[c][k] * W_ih[j][k]   (128 x 1024)
// ---------------------------------------------------------------------------
__global__ void pk(const float* __restrict__ emb, const float* __restrict__ Wih,
                   float* __restrict__ P) {
  __shared__ float e[EMBED];
  const int c = blockIdx.x >> 2;
  const int j = ((blockIdx.x & 3) << 8) + threadIdx.x;
  if (threadIdx.x < EMBED / 4) {
    reinterpret_cast<f32x4*>(e)[threadIdx.x] =
        reinterpret_cast<const f32x4*>(emb + c * EMBED)[threadIdx.x];
  }
  __syncthreads();
  const f32x4* w = reinterpret_cast<const f32x4*>(Wih + j * EMBED);
  float acc = 0.f;
#pragma unroll 8
  for (int k4 = 0; k4 < EMBED / 4; ++k4)
    acc += dot4(w[k4], reinterpret_cast<const f32x4*>(e)[k4]);
  P[c * HIDDEN + j] = acc;
}

// ---------------------------------------------------------------------------
// h[b][j] = h0[j];  zero the 8 group counters
// ---------------------------------------------------------------------------
__global__ void initk(const float* __restrict__ h0v, float* __restrict__ h,
                      int* __restrict__ ctr) {
  const int i = blockIdx.x * blockDim.x + threadIdx.x;
  h[i] = h0v[i & (HIDDEN - 1)];
  if (i < 8) ctr[i] = 0;
}

// ---------------------------------------------------------------------------
// Persistent RNN. Round-5's PROVEN fence protocol (compiler-generated
// acquire fence / release fetch_add, no inline asm), with:
//   - h deduped: one 32KB coherent read per block -> LDS (was 4x redundant)
//   - single release-counter per group (was 32-flag gather per poll iter)
// 256 blocks = 8 groups x 32 members; block = 256 threads (4 waves).
//   group g owns batch rows [8g,8g+8); member m owns W_hh rows [32m,32m+32)
//   in VGPRs. Per step:
//   poll ctr[g] >= 32*s (relaxed) -> acquire fence (agent) -> stage h -> LDS
//   -> 1024 FMA/thread -> LDS partial reduce -> tanh -> plain store slice
//   -> __syncthreads (drains vmem) -> tid0 fetch_add(ctr[g],1,RELEASE).
// WAR safety: ctr >= 32*s  =>  every member finished step s-1, and each
// member's h_{s-1} LOAD precedes its step-(s-1) publish in program order,
// so overwriting h_{s-1}'s buffer at step s is safe (ping-pong, +/-1 skew).
// Monotonic counter (0 -> 32*SEQ), re-zeroed by initk each call.
// ---------------------------------------------------------------------------
__global__ void __launch_bounds__(256, 1) persist4(
    float* __restrict__ ha, float* __restrict__ hb,
    const float* __restrict__ Whh, const float* __restrict__ P,
    const int* __restrict__ t, int* __restrict__ ctr) {
  __shared__ f32x4 h_lds[GB * 256];      // 32 KB staged h_s (f32x4 granules)
  __shared__ f32x4 part[64 * 64];        // [task][ks] 64 KB
  __shared__ int   t_lds[GB][SEQ];       // 16 KB
  __shared__ f32x4 P_lds[N_CHAR * 8];    // 16 KB   -> 128 KB total

  const int tid = threadIdx.x;
  const int jg = tid >> 6;            // wave id -> 8 j-rows
  const int ks = tid & 63;            // lane id -> 16 k's
  const int g = blockIdx.x >> 5;      // group
  const int m = blockIdx.x & 31;      // member
  const int b0 = g * GB;
  const int j0 = m * 32;

  // --- W_hh fragment (32 f32x4 = 128 VGPR), loaded once ---
  f32x4 w[2][4][4];
#pragma unroll
  for (int jql = 0; jql < 2; ++jql) {
#pragma unroll
    for (int jj = 0; jj < 4; ++jj) {
      const f32x4* wr = reinterpret_cast<const f32x4*>(
                            Whh + (j0 + jg * 8 + jql * 4 + jj) * HIDDEN) + ks;
      w[jql][jj][0] = wr[0];
      w[jql][jj][1] = wr[64];
      w[jql][jj][2] = wr[128];
      w[jql][jj][3] = wr[192];
    }
  }

  // --- preload t slice (8 rows) and P j-slice ---
#pragma unroll
  for (int i = 0; i < 4; ++i) {
    const int i4 = tid + 256 * i;
    const int row = i4 >> 7;
    const int col = (i4 & 127) * 4;
    *reinterpret_cast<int4*>(&t_lds[row][col]) =
        *reinterpret_cast<const int4*>(t + (b0 + row) * SEQ + col);
  }
#pragma unroll
  for (int i = 0; i < 4; ++i) {
    const int idx = tid + 256 * i;
    const int c = idx >> 3;
    const int gq = idx & 7;
    P_lds[idx] = reinterpret_cast<const f32x4*>(P + c * HIDDEN + j0)[gq];
  }
  __syncthreads();

  const float* cur = ha;
  float* nxt = hb;

  for (int s = 0; s < SEQ; ++s) {
    // --- wait: all 32 members published step s-1 (h_s ready) ---
    if (s > 0) {
      if (tid < 64) {
        const int want = s << 5;  // 32*s
        while (__hip_atomic_load(&ctr[g], __ATOMIC_RELAXED,
                                 __HIP_MEMORY_SCOPE_AGENT) < want) {
        }
        __builtin_amdgcn_fence(__ATOMIC_ACQUIRE, "agent");
      }
      __syncthreads();
    }

    // --- stage h_s (32 KB once per block) into LDS ---
    {
      const int row = (jg << 1) + (ks >> 5);   // wave stages 2 batch rows
      const int c5 = ks & 31;
      const f32x4* hp =
          reinterpret_cast<const f32x4*>(cur + (b0 + row) * HIDDEN) + c5;
      f32x4* hl = h_lds + row * 256 + c5;
#pragma unroll
      for (int q = 0; q < 8; ++q) hl[32 * q] = hp[32 * q];
    }
    __syncthreads();

    // --- compute: 8 bl x 8 j x 16 k = 1024 FMA/thread, h from LDS ---
    f32x4 acc[8][2];
#pragma unroll
    for (int bl = 0; bl < 8; ++bl) {
      const f32x4 hq0 = h_lds[bl * 256 + ks];
      const f32x4 hq1 = h_lds[bl * 256 + 64 + ks];
      const f32x4 hq2 = h_lds[bl * 256 + 128 + ks];
      const f32x4 hq3 = h_lds[bl * 256 + 192 + ks];
#pragma unroll
      for (int jql = 0; jql < 2; ++jql) {
        f32x4 a;
        a.x = dot4(w[jql][0][0], hq0) + dot4(w[jql][0][1], hq1) +
              dot4(w[jql][0][2], hq2) + dot4(w[jql][0][3], hq3);
        a.y = dot4(w[jql][1][0], hq0) + dot4(w[jql][1][1], hq1) +
              dot4(w[jql][1][2], hq2) + dot4(w[jql][1][3], hq3);
        a.z = dot4(w[jql][2][0], hq0) + dot4(w[jql][2][1], hq1) +
              dot4(w[jql][2][2], hq2) + dot4(w[jql][2][3], hq3);
        a.w = dot4(w[jql][3][0], hq0) + dot4(w[jql][3][1], hq1) +
              dot4(w[jql][3][2], hq2) + dot4(w[jql][3][3], hq3);
        acc[bl][jql] = a;
      }
    }

    // --- partials to LDS: [bl*8 + jg*2 + jql][ks], lanes consecutive ---
#pragma unroll
    for (int bl = 0; bl < 8; ++bl) {
#pragma unroll
      for (int jql = 0; jql < 2; ++jql)
        part[(bl * 8 + (jg << 1) + jql) * 64 + ks] = acc[bl][jql];
    }
    __syncthreads();

    // --- finish: 64 tasks x 4 lanes; lane sums 16 partials + 2 shfl ---
    {
      const int t4 = tid >> 2;          // task: bl = t4>>3, gq = t4&7
      const int q = tid & 3;
      const f32x4* p = &part[t4 * 64 + q * 16];
      f32x4 ssum = {0.f, 0.f, 0.f, 0.f};
#pragma unroll
      for (int i = 0; i < 16; ++i) {
        const f32x4 v = p[(i + tid) & 15];  // lane-rotated: even banks
        ssum.x += v.x; ssum.y += v.y; ssum.z += v.z; ssum.w += v.w;
      }
      ssum.x += __shfl_xor(ssum.x, 1); ssum.y += __shfl_xor(ssum.y, 1);
      ssum.z += __shfl_xor(ssum.z, 1); ssum.w += __shfl_xor(ssum.w, 1);
      ssum.x += __shfl_xor(ssum.x, 2); ssum.y += __shfl_xor(ssum.y, 2);
      ssum.z += __shfl_xor(ssum.z, 2); ssum.w += __shfl_xor(ssum.w, 2);
      if (q == 0) {
        const int bl = t4 >> 3;
        const int gq = t4 & 7;
        const int c = t_lds[bl][s];
        const f32x4 pq = P_lds[c * 8 + gq];
        f32x4 ho;
        ho.x = tanhf(pq.x + ssum.x);
        ho.y = tanhf(pq.y + ssum.y);
        ho.z = tanhf(pq.z + ssum.z);
        ho.w = tanhf(pq.w + ssum.w);
        *reinterpret_cast<f32x4*>(nxt + (b0 + bl) * HIDDEN + j0 + (gq << 2)) =
            ho;
      }
    }
    __syncthreads();  // all threads' slice stores drained (vmcnt) pre-publish

    // --- publish: release makes h_{s+1} globally visible before the add ---
    if (tid == 0) {
      __hip_atomic_fetch_add(&ctr[g], 1, __ATOMIC_RELEASE,
                             __HIP_MEMORY_SCOPE_AGENT);
    }

    const float* tmp = nxt; nxt = const_cast<float*>(cur); cur = tmp;
  }
}

// ---------------------------------------------------------------------------
// out[b][c] = sum_k h[b][k] * W_proj[c][k] + b_proj[c]
// ---------------------------------------------------------------------------
__global__ void outk(const float* __restrict__ h, const float* __restrict__ Wp,
                     const float* __restrict__ bp, float* __restrict__ out) {
  __shared__ float hbuf[HIDDEN];
  const int b = blockIdx.x;
  const int c = threadIdx.x;
  for (int i = threadIdx.x; i < HIDDEN / 4; i += blockDim.x) {
    reinterpret_cast<f32x4*>(hbuf)[i] =
        reinterpret_cast<const f32x4*>(h + b * HIDDEN)[i];
  }
  __syncthreads();
  const f32x4* w = reinterpret_cast<const f32x4*>(Wp + c * HIDDEN);
  float acc = 0.f;
#pragma unroll 8
  for (int k4 = 0; k4 < HIDDEN / 4; ++k4)
    acc += dot4(w[k4], reinterpret_cast<const f32x4*>(hbuf)[k4]);
  out[b * N_CHAR + c] = acc + bp[c];
}

// ---------------------------------------------------------------------------
extern "C" void kernel_launch(void* const* d_in, const int* in_sizes, int n_in,
                              void* d_out, int out_size, void* d_ws, size_t ws_size,
                              hipStream_t stream) {
  const int*   t   = (const int*)d_in[0];
  const float* emb = (const float*)d_in[1];
  const float* Wih = (const float*)d_in[2];
  const float* Whh = (const float*)d_in[3];
  const float* h0v = (const float*)d_in[4];
  const float* Wp  = (const float*)d_in[5];
  const float* bp  = (const float*)d_in[6];
  float* out = (float*)d_out;

  float* P  = (float*)d_ws;                 // 128*1024
  float* ha = P + N_CHAR * HIDDEN;          // 64*1024
  float* hb = ha + BATCH * HIDDEN;          // 64*1024
  int* ctr = (int*)(hb + BATCH * HIDDEN);   // 8 ints

  pk<<<512, 256, 0, stream>>>(emb, Wih, P);
  initk<<<256, 256, 0, stream>>>(h0v, ha, ctr);

  {
    float* a0 = ha; float* a1 = hb;
    const float* a2 = Whh; const float* a3 = P;
    const int* a4 = t; int* a5 = ctr;
    void* kargs[] = {&a0, &a1, &a2, &a3, &a4, &a5};
    (void)hipLaunchCooperativeKernel((const void*)persist4, dim3(256),
                                     dim3(256), kargs, 0, stream);
  }

  // SEQ even -> final state in ha
  outk<<<BATCH, 128, 0, stream>>>(ha, Wp, bp, out);
}